// Round 1
// baseline (2962.966 us; speedup 1.0000x reference)
//
#include <hip/hip_runtime.h>
#include <hip/hip_bf16.h>

#define G_    32
#define DIN   1024
#define DHID  2048
#define DOUT  1024
#define NTOK  2048

typedef __attribute__((ext_vector_type(8))) short bf16x8;
typedef __attribute__((ext_vector_type(4))) short bf16x4;
typedef __attribute__((ext_vector_type(4))) float f32x4;

// fp32 -> bf16 round-to-nearest-even (3 int ops; inputs are well-behaved Gaussians)
static __device__ __forceinline__ short f2b(float f) {
  unsigned u = __builtin_bit_cast(unsigned, f);
  u += 0x7fffu + ((u >> 16) & 1u);
  return (short)(u >> 16);
}

// ---------------------------------------------------------------------------
// Phase 1: hid[(tok_local*G + g)*DHID + h] = bf16( silu(x@gate_w) * (x@up_w) )
// grid = G * mtiles * 16 (nt fastest, g slowest for LLC locality), 256 thr
// ---------------------------------------------------------------------------
__global__ __launch_bounds__(256, 2)
void p1_gateup(const float* __restrict__ x, const float* __restrict__ gw,
               const float* __restrict__ uw, short* __restrict__ hid,
               int tok0, int mtiles) {
  __shared__ __align__(16) short As[128 * 32];
  __shared__ __align__(16) short Bg[128 * 32];
  __shared__ __align__(16) short Bu[128 * 32];

  const int b = blockIdx.x;
  const int nt = b & 15;
  const int rest = b >> 4;
  const int mtile = rest % mtiles;
  const int g = rest / mtiles;

  const int tid  = threadIdx.x;
  const int lane = tid & 63;
  const int wave = tid >> 6;
  const int wm = (wave >> 1) * 64;
  const int wn = (wave & 1) * 64;

  const size_t xrow = (size_t)G_ * DIN;  // token stride in x
  const float* xg  = x + ((size_t)(tok0 + mtile * 128) * G_ + g) * DIN;
  const float* gwg = gw + (size_t)g * DIN * DHID + nt * 128;
  const float* uwg = uw + (size_t)g * DIN * DHID + nt * 128;

  f32x4 accg[4][4], accu[4][4];
#pragma unroll
  for (int i = 0; i < 4; ++i)
#pragma unroll
    for (int j = 0; j < 4; ++j) {
      accg[i][j] = f32x4{0.f, 0.f, 0.f, 0.f};
      accu[i][j] = f32x4{0.f, 0.f, 0.f, 0.f};
    }

  // staging decomposition
  const int a_r = tid >> 3;        // 0..31 (rows, +32*p)
  const int a_c = (tid & 7) * 4;   // float col 0..28
  const int b_k = (tid >> 5) * 4;  // 0..28
  const int b_h = (tid & 31) * 4;  // 0..124

  const int fr = lane & 15;
  const int kq = (lane >> 4) * 8;

#pragma unroll 1
  for (int kt = 0; kt < DIN / 32; ++kt) {
    __syncthreads();
    // ---- stage A (x fp32 -> bf16), tile [128 rows][32 k] ----
    {
      const float* xp = xg + (size_t)a_r * xrow + kt * 32 + a_c;
#pragma unroll
      for (int p = 0; p < 4; ++p) {
        f32x4 v = *reinterpret_cast<const f32x4*>(xp + (size_t)(p * 32) * xrow);
        bf16x4 o = {f2b(v.x), f2b(v.y), f2b(v.z), f2b(v.w)};
        *reinterpret_cast<bf16x4*>(&As[(a_r + p * 32) * 32 + a_c]) = o;
      }
    }
    // ---- stage Bg/Bu transposed: LDS holds W^T [h][k] ----
    {
      const float* gp = gwg + (size_t)(kt * 32 + b_k) * DHID + b_h;
      const float* up = uwg + (size_t)(kt * 32 + b_k) * DHID + b_h;
      f32x4 gv[4], uv[4];
#pragma unroll
      for (int i = 0; i < 4; ++i) {
        gv[i] = *reinterpret_cast<const f32x4*>(gp + (size_t)i * DHID);
        uv[i] = *reinterpret_cast<const f32x4*>(up + (size_t)i * DHID);
      }
#pragma unroll
      for (int j = 0; j < 4; ++j) {
        bf16x4 og = {f2b(gv[0][j]), f2b(gv[1][j]), f2b(gv[2][j]), f2b(gv[3][j])};
        bf16x4 ou = {f2b(uv[0][j]), f2b(uv[1][j]), f2b(uv[2][j]), f2b(uv[3][j])};
        *reinterpret_cast<bf16x4*>(&Bg[(b_h + j) * 32 + b_k]) = og;
        *reinterpret_cast<bf16x4*>(&Bu[(b_h + j) * 32 + b_k]) = ou;
      }
    }
    __syncthreads();
    // ---- fragments + MFMA ----
    bf16x8 av[4], bgv[4], buv[4];
#pragma unroll
    for (int mi = 0; mi < 4; ++mi)
      av[mi] = *reinterpret_cast<const bf16x8*>(&As[(wm + mi * 16 + fr) * 32 + kq]);
#pragma unroll
    for (int ni = 0; ni < 4; ++ni) {
      bgv[ni] = *reinterpret_cast<const bf16x8*>(&Bg[(wn + ni * 16 + fr) * 32 + kq]);
      buv[ni] = *reinterpret_cast<const bf16x8*>(&Bu[(wn + ni * 16 + fr) * 32 + kq]);
    }
#pragma unroll
    for (int mi = 0; mi < 4; ++mi)
#pragma unroll
      for (int ni = 0; ni < 4; ++ni) {
        accg[mi][ni] = __builtin_amdgcn_mfma_f32_16x16x32_bf16(av[mi], bgv[ni], accg[mi][ni], 0, 0, 0);
        accu[mi][ni] = __builtin_amdgcn_mfma_f32_16x16x32_bf16(av[mi], buv[ni], accu[mi][ni], 0, 0, 0);
      }
  }

  // ---- epilogue: silu(g)*u -> bf16 hidden ----
  const int col = lane & 15;
  const int rb = (lane >> 4) * 4;
#pragma unroll
  for (int mi = 0; mi < 4; ++mi)
#pragma unroll
    for (int ni = 0; ni < 4; ++ni) {
      const int hc = nt * 128 + wn + ni * 16 + col;
#pragma unroll
      for (int r = 0; r < 4; ++r) {
        const int lrow = mtile * 128 + wm + mi * 16 + rb + r;
        const float gv = accg[mi][ni][r];
        const float uv = accu[mi][ni][r];
        const float s = gv / (1.0f + __expf(-gv)) * uv;
        hid[((size_t)lrow * G_ + g) * DHID + hc] = f2b(s);
      }
    }
}

// ---------------------------------------------------------------------------
// Phase 2: out[(tok*G + g)*DOUT + o] = hid @ down_w   (K = DHID)
// grid = G * mtiles * 8, 256 thr
// ---------------------------------------------------------------------------
__global__ __launch_bounds__(256, 2)
void p2_down(const short* __restrict__ hid, const float* __restrict__ dw,
             float* __restrict__ out, int tok0, int mtiles) {
  __shared__ __align__(16) short As[128 * 32];
  __shared__ __align__(16) short Bs[128 * 32];

  const int b = blockIdx.x;
  const int nt = b & 7;
  const int rest = b >> 3;
  const int mtile = rest % mtiles;
  const int g = rest / mtiles;

  const int tid  = threadIdx.x;
  const int lane = tid & 63;
  const int wave = tid >> 6;
  const int wm = (wave >> 1) * 64;
  const int wn = (wave & 1) * 64;

  const size_t hrow = (size_t)G_ * DHID;  // token stride in hid (chunk-local)
  const short* hg  = hid + ((size_t)(mtile * 128) * G_ + g) * DHID;
  const float* dwg = dw + (size_t)g * DHID * DOUT + nt * 128;

  f32x4 acc[4][4];
#pragma unroll
  for (int i = 0; i < 4; ++i)
#pragma unroll
    for (int j = 0; j < 4; ++j) acc[i][j] = f32x4{0.f, 0.f, 0.f, 0.f};

  const int a_r = tid >> 1;        // 0..127
  const int a_c = (tid & 1) * 16;  // short col 0 or 16
  const int b_k = (tid >> 5) * 4;
  const int b_h = (tid & 31) * 4;
  const int fr = lane & 15;
  const int kq = (lane >> 4) * 8;

#pragma unroll 1
  for (int kt = 0; kt < DHID / 32; ++kt) {
    __syncthreads();
    // ---- stage A (already bf16): [128][32] ----
    {
      const short* hp = hg + (size_t)a_r * hrow + kt * 32 + a_c;
      *reinterpret_cast<bf16x8*>(&As[a_r * 32 + a_c])     = *reinterpret_cast<const bf16x8*>(hp);
      *reinterpret_cast<bf16x8*>(&As[a_r * 32 + a_c + 8]) = *reinterpret_cast<const bf16x8*>(hp + 8);
    }
    // ---- stage B transposed ----
    {
      const float* dp = dwg + (size_t)(kt * 32 + b_k) * DOUT + b_h;
      f32x4 dv[4];
#pragma unroll
      for (int i = 0; i < 4; ++i)
        dv[i] = *reinterpret_cast<const f32x4*>(dp + (size_t)i * DOUT);
#pragma unroll
      for (int j = 0; j < 4; ++j) {
        bf16x4 o = {f2b(dv[0][j]), f2b(dv[1][j]), f2b(dv[2][j]), f2b(dv[3][j])};
        *reinterpret_cast<bf16x4*>(&Bs[(b_h + j) * 32 + b_k]) = o;
      }
    }
    __syncthreads();
    bf16x8 av[4], bv[4];
#pragma unroll
    for (int mi = 0; mi < 4; ++mi)
      av[mi] = *reinterpret_cast<const bf16x8*>(&As[(wm + mi * 16 + fr) * 32 + kq]);
#pragma unroll
    for (int ni = 0; ni < 4; ++ni)
      bv[ni] = *reinterpret_cast<const bf16x8*>(&Bs[(wn + ni * 16 + fr) * 32 + kq]);
#pragma unroll
    for (int mi = 0; mi < 4; ++mi)
#pragma unroll
      for (int ni = 0; ni < 4; ++ni)
        acc[mi][ni] = __builtin_amdgcn_mfma_f32_16x16x32_bf16(av[mi], bv[ni], acc[mi][ni], 0, 0, 0);
  }

  const int col = lane & 15;
  const int rb = (lane >> 4) * 4;
#pragma unroll
  for (int mi = 0; mi < 4; ++mi)
#pragma unroll
    for (int ni = 0; ni < 4; ++ni) {
      const int oc = nt * 128 + wn + ni * 16 + col;
#pragma unroll
      for (int r = 0; r < 4; ++r) {
        const int tok = tok0 + mtile * 128 + wm + mi * 16 + rb + r;
        out[((size_t)tok * G_ + g) * DOUT + oc] = acc[mi][ni][r];
      }
    }
}

extern "C" void kernel_launch(void* const* d_in, const int* in_sizes, int n_in,
                              void* d_out, int out_size, void* d_ws, size_t ws_size,
                              hipStream_t stream) {
  const float* x  = (const float*)d_in[0];
  const float* gw = (const float*)d_in[1];
  const float* uw = (const float*)d_in[2];
  const float* dw = (const float*)d_in[3];
  float* out = (float*)d_out;
  short* hid = (short*)d_ws;

  // hidden chunk: 128 tokens -> 128*G*DHID bf16 = 16 MiB
  const size_t bytes_per_mtile = (size_t)128 * G_ * DHID * sizeof(short);
  int mt_max = (int)(ws_size / bytes_per_mtile);
  if (mt_max < 1) return;  // workspace too small — signals ws_size < 16 MiB
  if (mt_max > 16) mt_max = 16;

  for (int t0 = 0; t0 < 16; t0 += mt_max) {
    int mt = 16 - t0 < mt_max ? 16 - t0 : mt_max;
    p1_gateup<<<dim3(G_ * mt * 16), dim3(256), 0, stream>>>(x, gw, uw, hid, t0 * 128, mt);
    p2_down<<<dim3(G_ * mt * 8), dim3(256), 0, stream>>>(hid, dw, out, t0 * 128, mt);
  }
}